// Round 14
// baseline (252.932 us; speedup 1.0000x reference)
//
#include <hip/hip_runtime.h>
#include <math.h>

#define B_SZ 2
#define LSEQ 1024
#define D_INP 1024
#define D_MODEL 2048
#define D_STATE 16
#define D_DISCR 128
#define MROWS (B_SZ * LSEQ)
#define NCH 64
#define CH 16

typedef __bf16 bf16x8 __attribute__((ext_vector_type(8)));
typedef float f32x4 __attribute__((ext_vector_type(4)));
typedef unsigned short ushort8 __attribute__((ext_vector_type(8)));

__device__ __forceinline__ float siluf(float x) { return x / (1.f + expf(-x)); }
__device__ __forceinline__ float softplusf(float x) {
    return fmaxf(x, 0.f) + log1pf(expf(-fabsf(x)));
}
__device__ __forceinline__ unsigned short f2b(float f) {
    unsigned u = __builtin_bit_cast(unsigned, f);
    u = u + 0x7fffu + ((u >> 16) & 1u);
    return (unsigned short)(u >> 16);
}
__device__ __forceinline__ float b2f(unsigned short u) {
    return __builtin_bit_cast(float, ((unsigned)u) << 16);
}

// ---------------------------------------------------------------------------
__global__ __launch_bounds__(256) void cast_all(
    const float* __restrict__ seq, const float* __restrict__ w_in,
    const float* __restrict__ w_out, const float* __restrict__ w_B,
    const float* __restrict__ w_C, const float* __restrict__ w_D1,
    const float* __restrict__ w_D2,
    unsigned short* __restrict__ seq_b, unsigned short* __restrict__ win_b,
    unsigned short* __restrict__ wout_b, unsigned short* __restrict__ wbcd_b,
    unsigned short* __restrict__ wd2_b)
{
    int i = blockIdx.x * 256 + threadIdx.x;
    const float* src; unsigned short* dst; int off;
    if      (i < 262144)  { src = seq;  dst = seq_b;          off = i; }
    else if (i < 786432)  { src = w_in; dst = win_b;          off = i - 262144; }
    else if (i < 1048576) { src = w_out; dst = wout_b;        off = i - 786432; }
    else if (i < 1052672) { src = w_B;  dst = wbcd_b;         off = i - 1048576; }
    else if (i < 1056768) { src = w_C;  dst = wbcd_b + 32768; off = i - 1052672; }
    else if (i < 1089536) { src = w_D1; dst = wbcd_b + 65536; off = i - 1056768; }
    else if (i < 1122304) { src = w_D2; dst = wd2_b;          off = i - 1089536; }
    else return;
    const float4* p = (const float4*)(src + (size_t)off * 8);
    float4 a = p[0], b = p[1];
    ushort8 o = {f2b(a.x), f2b(a.y), f2b(a.z), f2b(a.w),
                 f2b(b.x), f2b(b.y), f2b(b.z), f2b(b.w)};
    *(ushort8*)(dst + (size_t)off * 8) = o;
}

// ---------------------------------------------------------------------------
// bf16 MFMA GEMM-NT, R12 single-slab-prefetch dbuf core, now 64x64 tiles:
// 16 KB LDS + ~55 VGPR -> 8 blocks/CU (32 waves, 100% occupancy). R13
// showed the 128x64 kernel at 4 blocks/CU is latency-bound with counters
// insensitive to staging style — the missing term is waves, not issue work.
// 4 waves in 2x2 quadrants (NI=NJ=2). XOR-swizzled LDS chunks
// (q ^ ((r>>1)&3)) -> 0 bank conflicts (R8). 1 barrier/K-iter; next-slab
// loads issue pre-MFMA so the vmcnt wait lands post-MFMA (R10/R12 proven;
// R11 depth-2 regressed - do not deepen).
// Block does K-chunk [z*K, z*K+K) -> Cbase + z*partStride.
// B rows past N read unguarded (must be allocated); masked at store.
// epi: 0 fp32 store; 2 softplus(bias[col]+acc) -> bf16 (Cbase as u16);
//      5 split both-bf16: col<2048 -> (u16*)Cbase, col>=2048 -> C2.
__global__ __launch_bounds__(256) void gemm64(
    const unsigned short* __restrict__ A, int lda,
    const unsigned short* __restrict__ B, int ldb,
    float* __restrict__ Cbase, int ldc, size_t partStride,
    int N, int K, const float* __restrict__ bias,
    unsigned short* __restrict__ C2, int epi)
{
    __shared__ unsigned short As[2][64 * 32];
    __shared__ unsigned short Bs[2][64 * 32];
    const int t = threadIdx.x;
    const int w = t >> 6, lane = t & 63;
    const int fr = lane & 15, fq = lane >> 4;
    const int row0 = blockIdx.y * 64, col0 = blockIdx.x * 64;
    const int kz = blockIdx.z * K;
    const int sr = t >> 2, sq = t & 3;         // 64 rows x 4 chunks
    const int sqz = sq ^ ((sr >> 1) & 3);      // swizzled store chunk
    const int qa = fq ^ ((fr >> 1) & 3);       // swizzled read chunk

    const int rbase = (w & 1) * 32;            // 2x2 wave quadrants
    const int cbase = (w >> 1) * 32;

    const unsigned short* gA0 = A + (size_t)(row0 + sr) * lda + kz + sq * 8;
    const unsigned short* gB0 = B + (size_t)(col0 + sr) * ldb + kz + sq * 8;

    f32x4 acc[2][2];
#pragma unroll
    for (int i = 0; i < 2; i++)
#pragma unroll
        for (int j = 0; j < 2; j++) acc[i][j] = (f32x4){0.f, 0.f, 0.f, 0.f};

    // prologue: slab 0 -> buffer 0
    ushort8 a0 = *(const ushort8*)gA0;
    ushort8 b0 = *(const ushort8*)gB0;
    *(ushort8*)&As[0][sr * 32 + sqz * 8] = a0;
    *(ushort8*)&Bs[0][sr * 32 + sqz * 8] = b0;
    __syncthreads();

    int buf = 0;
    for (int k0 = 0; k0 < K; k0 += 32) {
        const bool more = (k0 + 32 < K);
        if (more) {                            // next-slab loads in flight
            gA0 += 32; gB0 += 32;
            a0 = *(const ushort8*)gA0;
            b0 = *(const ushort8*)gB0;
        }
        bf16x8 af[2], bfr[2];
#pragma unroll
        for (int i = 0; i < 2; i++) {
            ushort8 u = *(const ushort8*)&As[buf][(rbase + i * 16 + fr) * 32 + qa * 8];
            af[i] = __builtin_bit_cast(bf16x8, u);
        }
#pragma unroll
        for (int j = 0; j < 2; j++) {
            ushort8 u = *(const ushort8*)&Bs[buf][(cbase + j * 16 + fr) * 32 + qa * 8];
            bfr[j] = __builtin_bit_cast(bf16x8, u);
        }
#pragma unroll
        for (int i = 0; i < 2; i++)
#pragma unroll
            for (int j = 0; j < 2; j++)
                acc[i][j] = __builtin_amdgcn_mfma_f32_16x16x32_bf16(
                    af[i], bfr[j], acc[i][j], 0, 0, 0);
        if (more) {
            int nb = buf ^ 1;                  // vmcnt wait lands here, post-MFMA
            *(ushort8*)&As[nb][sr * 32 + sqz * 8] = a0;
            *(ushort8*)&Bs[nb][sr * 32 + sqz * 8] = b0;
            __syncthreads();
            buf = nb;
        }
    }

    float* C = Cbase + (size_t)blockIdx.z * partStride;
#pragma unroll
    for (int i = 0; i < 2; i++) {
#pragma unroll
        for (int r = 0; r < 4; r++) {
            int row = row0 + rbase + i * 16 + fq * 4 + r;
#pragma unroll
            for (int j = 0; j < 2; j++) {      // j-inner: contiguous write runs
                int col = col0 + cbase + j * 16 + fr;
                if (col >= N) continue;
                float v = acc[i][j][r];
                if (epi == 0) C[(size_t)row * ldc + col] = v;
                else if (epi == 2)
                    ((unsigned short*)Cbase)[(size_t)row * ldc + col] =
                        f2b(softplusf(bias[col] + v));
                else {
                    unsigned short v16 = f2b(v);
                    if (col < 2048) ((unsigned short*)Cbase)[(size_t)row * 2048 + col] = v16;
                    else C2[(size_t)row * 2048 + col - 2048] = v16;
                }
            }
        }
    }
}

// ---------------------------------------------------------------------------
__global__ __launch_bounds__(256) void bcd_reduce(
    const float* __restrict__ part, unsigned short* __restrict__ bcdB,
    float* __restrict__ bc32)
{
    int t = blockIdx.x * 256 + threadIdx.x;
    if (t >= 327680) return;
    float s = 0.f;
#pragma unroll
    for (int z = 0; z < 8; z++) s += part[(size_t)z * 327680 + t];
    bcdB[t] = f2b(s);
    int col = t % 160;
    if (col < 32) bc32[(size_t)(t / 160) * 32 + col] = s;
}

// sum 4 split-K partials of gemm6 -> final out
__global__ __launch_bounds__(256) void out_reduce(
    const float* __restrict__ part, float* __restrict__ out)
{
    int i = blockIdx.x * 256 + threadIdx.x;    // 524288 float4 groups
    float4 p0 = ((const float4*)part)[i];
    float4 p1 = ((const float4*)(part + 2097152))[i];
    float4 p2 = ((const float4*)(part + 4194304))[i];
    float4 p3 = ((const float4*)(part + 6291456))[i];
    float4 o = {p0.x + p1.x + p2.x + p3.x, p0.y + p1.y + p2.y + p3.y,
                p0.z + p1.z + p2.z + p3.z, p0.w + p1.w + p2.w + p3.w};
    ((float4*)out)[i] = o;
}

// ---------------------------------------------------------------------------
// depthwise causal conv1d (K=4) + bias + SiLU; bf16 in/out, 8 d's per thread
__global__ __launch_bounds__(256) void conv_silu8(
    const unsigned short* __restrict__ aB,
    const float* __restrict__ cw, const float* __restrict__ cb,
    unsigned short* __restrict__ aConvB)
{
    int idx = blockIdx.x * 256 + threadIdx.x;      // 524288
    int d8 = (idx & 255) << 3;
    int bl = idx >> 8;
    int l = bl & (LSEQ - 1);
    const unsigned short* base = aB + (size_t)bl * 2048 + d8;
    const ushort8 z8 = {0, 0, 0, 0, 0, 0, 0, 0};
    ushort8 x0 = *(const ushort8*)base;
    ushort8 x1 = (l >= 1) ? *(const ushort8*)(base - 2048) : z8;
    ushort8 x2 = (l >= 2) ? *(const ushort8*)(base - 2 * 2048) : z8;
    ushort8 x3 = (l >= 3) ? *(const ushort8*)(base - 3 * 2048) : z8;
    float4 cb0 = *(const float4*)(cb + d8);
    float4 cb1 = *(const float4*)(cb + d8 + 4);
    float bv[8] = {cb0.x, cb0.y, cb0.z, cb0.w, cb1.x, cb1.y, cb1.z, cb1.w};
    ushort8 o;
#pragma unroll
    for (int j = 0; j < 8; j++) {
        float4 wv = *(const float4*)(cw + (size_t)(d8 + j) * 4);
        float acc = bv[j];
        acc = fmaf(b2f(x0[j]), wv.w, acc);
        acc = fmaf(b2f(x1[j]), wv.z, acc);
        acc = fmaf(b2f(x2[j]), wv.y, acc);
        acc = fmaf(b2f(x3[j]), wv.x, acc);
        o[j] = f2b(siluf(acc));
    }
    *(ushort8*)(aConvB + (size_t)bl * 2048 + d8) = o;
}

// ---------------------------------------------------------------------------
// Chunk-parallel scan, 64 chunks x 16 steps, bf16 datapath incl. hend.
// prod factorization: chunk prod[s] = expA[s]^CH * prod(delta).
// hendB idx(b,c,s,d) = (((b*64+c)*16+s)<<11)+d ; P idx = (b*64+c)*2048+d.
__global__ __launch_bounds__(256) void scan_phaseA(
    const unsigned short* __restrict__ deltaB,
    const unsigned short* __restrict__ aConvB,
    const float* __restrict__ bc32, const float* __restrict__ A_param,
    unsigned short* __restrict__ hendB, float* __restrict__ Pd)
{
    int blk = blockIdx.x;                      // 1024
    int d = ((blk & 7) << 8) + threadIdx.x;
    int c = (blk >> 3) & 63;
    int b = blk >> 9;
    float expA[16], h[16];
#pragma unroll
    for (int s = 0; s < 16; s++) {
        expA[s] = expf(-A_param[d * 16 + s]);
        h[s] = 0.f;
    }
    float P = 1.f;
    int r0 = b * LSEQ + c * CH;
    const unsigned short* dp = deltaB + (size_t)r0 * D_MODEL + d;
    const unsigned short* ap = aConvB + (size_t)r0 * D_MODEL + d;
    const float4* bp = (const float4*)(bc32 + (size_t)r0 * 32);
    float dlt = b2f(*dp), av = b2f(*ap);
    float4 B0 = bp[0], B1 = bp[1], B2 = bp[2], B3 = bp[3];
    for (int l = 0; l < CH; l++) {
        dp += 2048; ap += 2048; bp += 8;       // prefetch l+1 (lands in ws, safe)
        float nd = b2f(*dp), na = b2f(*ap);
        float4 nB0 = bp[0], nB1 = bp[1], nB2 = bp[2], nB3 = bp[3];
        float Bv[16] = {B0.x, B0.y, B0.z, B0.w, B1.x, B1.y, B1.z, B1.w,
                        B2.x, B2.y, B2.z, B2.w, B3.x, B3.y, B3.z, B3.w};
        float x = dlt * av;
        P *= dlt;
#pragma unroll
        for (int s = 0; s < 16; s++)
            h[s] = fmaf(expA[s] * dlt, h[s], Bv[s] * x);
        dlt = nd; av = na; B0 = nB0; B1 = nB1; B2 = nB2; B3 = nB3;
    }
    size_t base = (((size_t)(b * 64 + c) * 16) << 11) + d;
#pragma unroll
    for (int s = 0; s < 16; s++)
        hendB[base + ((size_t)s << 11)] = f2b(h[s]);
    Pd[(size_t)(b * 64 + c) * 2048 + d] = P;
}

// chunk prefix: overwrite hendB[c] with state ENTERING chunk c
__global__ __launch_bounds__(256) void scan_phaseB2(
    unsigned short* __restrict__ hendB, const float* __restrict__ Pd,
    const float* __restrict__ A_param)
{
    int t = blockIdx.x * 256 + threadIdx.x;    // 65536
    int d = t & 2047, s = (t >> 11) & 15, b = t >> 15;
    float e = expf(-A_param[d * 16 + s]);
    float e2 = e * e, e4 = e2 * e2, e8 = e4 * e4;
    float eCH = e8 * e8;                       // expA^16
    size_t idx = (((size_t)(b * 64) * 16 + s) << 11) + d;
    const size_t cs = (size_t)16 << 11;
    size_t pidx = (size_t)(b * 64) * 2048 + d;
    float h = 0.f;
    float he = b2f(hendB[idx]), P = Pd[pidx];
    for (int c = 0; c < NCH; c++) {
        size_t nidx = idx + cs;
        float nhe = b2f(hendB[nidx]);          // prefetch (lands in ws, safe)
        float nP = Pd[pidx + 2048];
        hendB[idx] = f2b(h);
        h = fmaf(eCH * P, h, he);
        idx = nidx; pidx += 2048; he = nhe; P = nP;
    }
}

__global__ __launch_bounds__(256) void scan_phaseC(
    const unsigned short* __restrict__ deltaB,
    const unsigned short* __restrict__ aConvB,
    const unsigned short* __restrict__ gateB,
    const float* __restrict__ bc32,
    const float* __restrict__ A_param, const float* __restrict__ D_param,
    const unsigned short* __restrict__ hendB, unsigned short* __restrict__ outB)
{
    int blk = blockIdx.x;                      // 1024
    int d = ((blk & 7) << 8) + threadIdx.x;
    int c = (blk >> 3) & 63;
    int b = blk >> 9;
    float expA[16], h[16];
    size_t base = (((size_t)(b * 64 + c) * 16) << 11) + d;
#pragma unroll
    for (int s = 0; s < 16; s++) {
        expA[s] = expf(-A_param[d * 16 + s]);
        h[s] = b2f(hendB[base + ((size_t)s << 11)]);
    }
    float Dp = D_param[d];
    int r0 = b * LSEQ + c * CH;
    const unsigned short* dp = deltaB + (size_t)r0 * D_MODEL + d;
    const unsigned short* ap = aConvB + (size_t)r0 * D_MODEL + d;
    const unsigned short* gp = gateB + (size_t)r0 * 2048 + d;
    const float4* bp = (const float4*)(bc32 + (size_t)r0 * 32);
    unsigned short* op = outB + (size_t)r0 * D_MODEL + d;
    float dlt = b2f(*dp), av = b2f(*ap), g = b2f(*gp);
    float4 B0 = bp[0], B1 = bp[1], B2 = bp[2], B3 = bp[3];
    float4 C0 = bp[4], C1 = bp[5], C2 = bp[6], C3 = bp[7];
    for (int l = 0; l < CH; l++) {
        dp += 2048; ap += 2048; gp += 2048; bp += 8;
        float nd = b2f(*dp), na = b2f(*ap), ng = b2f(*gp);
        float4 nB0 = bp[0], nB1 = bp[1], nB2 = bp[2], nB3 = bp[3];
        float4 nC0 = bp[4], nC1 = bp[5], nC2 = bp[6], nC3 = bp[7];
        float Bv[16] = {B0.x, B0.y, B0.z, B0.w, B1.x, B1.y, B1.z, B1.w,
                        B2.x, B2.y, B2.z, B2.w, B3.x, B3.y, B3.z, B3.w};
        float Cv[16] = {C0.x, C0.y, C0.z, C0.w, C1.x, C1.y, C1.z, C1.w,
                        C2.x, C2.y, C2.z, C2.w, C3.x, C3.y, C3.z, C3.w};
        float x = dlt * av;
        float acc = 0.f;
#pragma unroll
        for (int s = 0; s < 16; s++) {
            float Ab = expA[s] * dlt;
            h[s] = fmaf(Ab, h[s], Bv[s] * x);
            acc = fmaf(h[s], Cv[s], acc);
        }
        *op = f2b((acc + Dp * av) * siluf(g));
        op += D_MODEL;
        dlt = nd; av = na; g = ng;
        B0 = nB0; B1 = nB1; B2 = nB2; B3 = nB3;
        C0 = nC0; C1 = nC1; C2 = nC2; C3 = nC3;
    }
}

extern "C" void kernel_launch(void* const* d_in, const int* in_sizes, int n_in,
                              void* d_out, int out_size, void* d_ws, size_t ws_size,
                              hipStream_t stream) {
    const float* seq = (const float*)d_in[0];
    const float* w_in = (const float*)d_in[1];
    const float* w_out = (const float*)d_in[2];
    const float* w_B = (const float*)d_in[3];
    const float* w_C = (const float*)d_in[4];
    const float* w_D1 = (const float*)d_in[5];
    const float* w_D2 = (const float*)d_in[6];
    const float* conv_w = (const float*)d_in[7];
    const float* conv_b = (const float*)d_in[8];
    const float* A_param = (const float*)d_in[9];
    const float* D_param = (const float*)d_in[10];
    float* out = (float*)d_out;

    // fp32 region (floats)
    float* bc32  = (float*)d_ws;                   // 65,536
    float* part  = bc32 + (size_t)65536;           // 2,621,440 (dead after reduce)
    float* part6 = part + (size_t)2621440;         // 8,388,608 (gemm6 partials)
    float* Pd    = part;                           // overlay: 262,144 ✓ (part dead)
    unsigned short* hendB = (unsigned short*)part6;  // overlay: 4,194,304 u16 =
                                                   //  2,097,152 floats ✓ (dead
                                                   //  before gemm6 writes part6)
    // bf16 region
    unsigned short* seq_b  = (unsigned short*)(part6 + 8388608);
    unsigned short* win_b  = seq_b + (size_t)2097152;
    unsigned short* wout_b = win_b + (size_t)4194304;
    unsigned short* wbcd_b = wout_b + (size_t)2097152;  // [160,2048]
    unsigned short* wd2_b  = wbcd_b + (size_t)327680;   // [2048,128]
    unsigned short* aB     = wd2_b + (size_t)262144;    // [2048,2048]
    unsigned short* aConvB = aB + (size_t)4194304;      // [2048,2048]
    unsigned short* deltaB = aConvB + (size_t)4194304;  // [2048,2048]
    unsigned short* gateB  = deltaB + (size_t)4194304;  // [2048,2048]
    unsigned short* outB   = gateB + (size_t)4194304;   // [2048,2048]
    unsigned short* bcdB   = outB + (size_t)4194304;    // [2048,160]

    // 0) casts
    cast_all<<<dim3(4384), 256, 0, stream>>>(seq, w_in, w_out, w_B, w_C, w_D1, w_D2,
                                             seq_b, win_b, wout_b, wbcd_b, wd2_b);
    // 1) [a|gate] = seq @ w_in^T  [2048 x 4096] K=1024 -> 2048 blocks, 8/CU
    gemm64<<<dim3(64, 32), 256, 0, stream>>>(seq_b, 1024, win_b, 1024,
                                             (float*)aB, 2048, 0, 4096, 1024,
                                             nullptr, gateB, 5);
    // 2) conv + SiLU (bf16 in/out, 8-wide)
    conv_silu8<<<dim3(2048), 256, 0, stream>>>(aB, conv_w, conv_b, aConvB);
    // 3) bcd split-K x8 -> 768 blocks (x=2 cols 128..191 read OOB rows of
    //    wbcd_b into wd2_b — allocated, masked at store)
    gemm64<<<dim3(3, 32, 8), 256, 0, stream>>>(aConvB, 2048, wbcd_b, 2048,
                                               part, 160, 327680, 160, 256,
                                               nullptr, nullptr, 0);
    bcd_reduce<<<dim3(1280), 256, 0, stream>>>(part, bcdB, bc32);
    // 4) deltaB = bf16(softplus(D + d1 @ wD2^T))  [2048 x 2048] K=128 -> 1024 blocks
    gemm64<<<dim3(32, 32), 256, 0, stream>>>(bcdB + 32, 160, wd2_b, 128,
                                             (float*)deltaB, 2048, 0, 2048, 128,
                                             D_param, nullptr, 2);
    // 5) chunk-parallel scan (64 chunks x 16 steps; bf16 datapath incl. hend)
    scan_phaseA<<<dim3(1024), 256, 0, stream>>>(deltaB, aConvB, bc32, A_param,
                                                hendB, Pd);
    scan_phaseB2<<<dim3(256), 256, 0, stream>>>(hendB, Pd, A_param);
    scan_phaseC<<<dim3(1024), 256, 0, stream>>>(deltaB, aConvB, gateB, bc32,
                                                A_param, D_param, hendB, outB);
    // 6) out = ssm_out @ w_out^T  [2048 x 1024] K=2048, split-K x4 -> 2048 blocks
    gemm64<<<dim3(16, 32, 4), 256, 0, stream>>>(outB, 2048, wout_b, 2048,
                                                part6, 1024, 2097152, 1024, 512,
                                                nullptr, nullptr, 0);
    out_reduce<<<dim3(2048), 256, 0, stream>>>(part6, out);
}

// Round 15
// 249.649 us; speedup vs baseline: 1.0132x; 1.0132x over previous
//
#include <hip/hip_runtime.h>
#include <math.h>

#define B_SZ 2
#define LSEQ 1024
#define D_INP 1024
#define D_MODEL 2048
#define D_STATE 16
#define D_DISCR 128
#define MROWS (B_SZ * LSEQ)
#define NCH 64
#define CH 16

typedef __bf16 bf16x8 __attribute__((ext_vector_type(8)));
typedef float f32x4 __attribute__((ext_vector_type(4)));
typedef unsigned short ushort8 __attribute__((ext_vector_type(8)));

__device__ __forceinline__ float siluf(float x) { return x / (1.f + expf(-x)); }
__device__ __forceinline__ float softplusf(float x) {
    return fmaxf(x, 0.f) + log1pf(expf(-fabsf(x)));
}
__device__ __forceinline__ unsigned short f2b(float f) {
    unsigned u = __builtin_bit_cast(unsigned, f);
    u = u + 0x7fffu + ((u >> 16) & 1u);
    return (unsigned short)(u >> 16);
}
__device__ __forceinline__ float b2f(unsigned short u) {
    return __builtin_bit_cast(float, ((unsigned)u) << 16);
}

// ---------------------------------------------------------------------------
__global__ __launch_bounds__(256) void cast_all(
    const float* __restrict__ seq, const float* __restrict__ w_in,
    const float* __restrict__ w_out, const float* __restrict__ w_B,
    const float* __restrict__ w_C, const float* __restrict__ w_D1,
    const float* __restrict__ w_D2,
    unsigned short* __restrict__ seq_b, unsigned short* __restrict__ win_b,
    unsigned short* __restrict__ wout_b, unsigned short* __restrict__ wbcd_b,
    unsigned short* __restrict__ wd2_b)
{
    int i = blockIdx.x * 256 + threadIdx.x;
    const float* src; unsigned short* dst; int off;
    if      (i < 262144)  { src = seq;  dst = seq_b;          off = i; }
    else if (i < 786432)  { src = w_in; dst = win_b;          off = i - 262144; }
    else if (i < 1048576) { src = w_out; dst = wout_b;        off = i - 786432; }
    else if (i < 1052672) { src = w_B;  dst = wbcd_b;         off = i - 1048576; }
    else if (i < 1056768) { src = w_C;  dst = wbcd_b + 32768; off = i - 1052672; }
    else if (i < 1089536) { src = w_D1; dst = wbcd_b + 65536; off = i - 1056768; }
    else if (i < 1122304) { src = w_D2; dst = wd2_b;          off = i - 1089536; }
    else return;
    const float4* p = (const float4*)(src + (size_t)off * 8);
    float4 a = p[0], b = p[1];
    ushort8 o = {f2b(a.x), f2b(a.y), f2b(a.z), f2b(a.w),
                 f2b(b.x), f2b(b.y), f2b(b.z), f2b(b.w)};
    *(ushort8*)(dst + (size_t)off * 8) = o;
}

// ---------------------------------------------------------------------------
// bf16 MFMA GEMM-NT — the R12 local-optimum configuration (verified best of
// R5..R14 sweep): 128xTN tile, BK=32, VGPR-staged single-slab-prefetch
// double buffer, 1 barrier/K-iter, XOR-swizzled unpadded LDS (0 conflicts).
// Tile-space evidence: 128x64 @ 4 blocks/CU = 41 µs (R12); 64x64 @ 8/CU =
// 51 µs (R14, halved MFMA-per-barrier); depth-2 pipeline = 54 µs (R11);
// global_load_lds staging = neutral (R13). ~390 TF on M2048/N4096/K1024
// matches the m102 shape-curve plateau for source-level K-loops.
// Block does K-chunk [z*K, z*K+K) -> Cbase + z*partStride.
// TN=128: 4 waves 2x2, 4x4 frags; TN=64: waves row-stacked, 2x4 frags.
// B rows past N read unguarded (must be allocated); masked at store.
// epi: 0 fp32 store; 2 softplus(bias[col]+acc) -> bf16 (Cbase as u16);
//      5 split both-bf16: col<2048 -> (u16*)Cbase, col>=2048 -> C2.
template <int TN>
__global__ __launch_bounds__(256) void gemm_db(
    const unsigned short* __restrict__ A, int lda,
    const unsigned short* __restrict__ B, int ldb,
    float* __restrict__ Cbase, int ldc, size_t partStride,
    int N, int K, const float* __restrict__ bias,
    unsigned short* __restrict__ C2, int epi)
{
    __shared__ unsigned short As[2][128 * 32];
    __shared__ unsigned short Bs[2][TN * 32];
    const int t = threadIdx.x;
    const int w = t >> 6, lane = t & 63;
    const int fr = lane & 15, fq = lane >> 4;
    const int row0 = blockIdx.y * 128, col0 = blockIdx.x * TN;
    const int kz = blockIdx.z * K;
    const int sr = t >> 2, sq = t & 3;
    const int sqz = sq ^ ((sr >> 1) & 3);      // swizzled store chunk
    const int qa = fq ^ ((fr >> 1) & 3);       // swizzled read chunk

    constexpr int NI = (TN == 128) ? 4 : 2;
    const int rbase = (TN == 128) ? (w >> 1) * 64 : w * 32;
    const int cbase = (TN == 128) ? (w & 1) * 64 : 0;

    const unsigned short* gA0 = A + (size_t)(row0 + sr) * lda + kz + sq * 8;
    const unsigned short* gA1 = gA0 + (size_t)64 * lda;
    const unsigned short* gB0 = B + (size_t)(col0 + sr) * ldb + kz + sq * 8;
    const unsigned short* gB1 = gB0 + (size_t)64 * ldb;

    f32x4 acc[NI][4];
#pragma unroll
    for (int i = 0; i < NI; i++)
#pragma unroll
        for (int j = 0; j < 4; j++) acc[i][j] = (f32x4){0.f, 0.f, 0.f, 0.f};

    // prologue: stage slab 0 into buffer 0
    ushort8 a0 = *(const ushort8*)gA0;
    ushort8 a1 = *(const ushort8*)gA1;
    ushort8 b0 = *(const ushort8*)gB0;
    ushort8 b1;
    if (TN == 128) b1 = *(const ushort8*)gB1;
    *(ushort8*)&As[0][sr * 32 + sqz * 8] = a0;
    *(ushort8*)&As[0][(64 + sr) * 32 + sqz * 8] = a1;
    *(ushort8*)&Bs[0][sr * 32 + sqz * 8] = b0;
    if (TN == 128) *(ushort8*)&Bs[0][(64 + sr) * 32 + sqz * 8] = b1;
    __syncthreads();

    int buf = 0;
    for (int k0 = 0; k0 < K; k0 += 32) {
        const bool more = (k0 + 32 < K);
        if (more) {                        // next-slab loads in flight
            gA0 += 32; gA1 += 32; gB0 += 32; gB1 += 32;
            a0 = *(const ushort8*)gA0;
            a1 = *(const ushort8*)gA1;
            b0 = *(const ushort8*)gB0;
            if (TN == 128) b1 = *(const ushort8*)gB1;
        }
        bf16x8 af[NI], bfr[4];
#pragma unroll
        for (int i = 0; i < NI; i++) {
            ushort8 u = *(const ushort8*)&As[buf][(rbase + i * 16 + fr) * 32 + qa * 8];
            af[i] = __builtin_bit_cast(bf16x8, u);
        }
#pragma unroll
        for (int j = 0; j < 4; j++) {
            ushort8 u = *(const ushort8*)&Bs[buf][(cbase + j * 16 + fr) * 32 + qa * 8];
            bfr[j] = __builtin_bit_cast(bf16x8, u);
        }
#pragma unroll
        for (int i = 0; i < NI; i++)
#pragma unroll
            for (int j = 0; j < 4; j++)
                acc[i][j] = __builtin_amdgcn_mfma_f32_16x16x32_bf16(
                    af[i], bfr[j], acc[i][j], 0, 0, 0);
        if (more) {
            int nb = buf ^ 1;              // vmcnt wait lands here, post-MFMA
            *(ushort8*)&As[nb][sr * 32 + sqz * 8] = a0;
            *(ushort8*)&As[nb][(64 + sr) * 32 + sqz * 8] = a1;
            *(ushort8*)&Bs[nb][sr * 32 + sqz * 8] = b0;
            if (TN == 128) *(ushort8*)&Bs[nb][(64 + sr) * 32 + sqz * 8] = b1;
            __syncthreads();
            buf = nb;
        }
    }

    float* C = Cbase + (size_t)blockIdx.z * partStride;
#pragma unroll
    for (int i = 0; i < NI; i++) {
#pragma unroll
        for (int r = 0; r < 4; r++) {
            int row = row0 + rbase + i * 16 + fq * 4 + r;
#pragma unroll
            for (int j = 0; j < 4; j++) {   // j-inner: contiguous write runs
                int col = col0 + cbase + j * 16 + fr;
                if (col >= N) continue;
                float v = acc[i][j][r];
                if (epi == 0) C[(size_t)row * ldc + col] = v;
                else if (epi == 2)
                    ((unsigned short*)Cbase)[(size_t)row * ldc + col] =
                        f2b(softplusf(bias[col] + v));
                else {
                    unsigned short v16 = f2b(v);
                    if (col < 2048) ((unsigned short*)Cbase)[(size_t)row * 2048 + col] = v16;
                    else C2[(size_t)row * 2048 + col - 2048] = v16;
                }
            }
        }
    }
}

// ---------------------------------------------------------------------------
__global__ __launch_bounds__(256) void bcd_reduce(
    const float* __restrict__ part, unsigned short* __restrict__ bcdB,
    float* __restrict__ bc32)
{
    int t = blockIdx.x * 256 + threadIdx.x;
    if (t >= 327680) return;
    float s = 0.f;
#pragma unroll
    for (int z = 0; z < 8; z++) s += part[(size_t)z * 327680 + t];
    bcdB[t] = f2b(s);
    int col = t % 160;
    if (col < 32) bc32[(size_t)(t / 160) * 32 + col] = s;
}

// sum 4 split-K partials of gemm6 -> final out
__global__ __launch_bounds__(256) void out_reduce(
    const float* __restrict__ part, float* __restrict__ out)
{
    int i = blockIdx.x * 256 + threadIdx.x;    // 524288 float4 groups
    float4 p0 = ((const float4*)part)[i];
    float4 p1 = ((const float4*)(part + 2097152))[i];
    float4 p2 = ((const float4*)(part + 4194304))[i];
    float4 p3 = ((const float4*)(part + 6291456))[i];
    float4 o = {p0.x + p1.x + p2.x + p3.x, p0.y + p1.y + p2.y + p3.y,
                p0.z + p1.z + p2.z + p3.z, p0.w + p1.w + p2.w + p3.w};
    ((float4*)out)[i] = o;
}

// ---------------------------------------------------------------------------
// depthwise causal conv1d (K=4) + bias + SiLU; bf16 in/out, 8 d's per thread
__global__ __launch_bounds__(256) void conv_silu8(
    const unsigned short* __restrict__ aB,
    const float* __restrict__ cw, const float* __restrict__ cb,
    unsigned short* __restrict__ aConvB)
{
    int idx = blockIdx.x * 256 + threadIdx.x;      // 524288
    int d8 = (idx & 255) << 3;
    int bl = idx >> 8;
    int l = bl & (LSEQ - 1);
    const unsigned short* base = aB + (size_t)bl * 2048 + d8;
    const ushort8 z8 = {0, 0, 0, 0, 0, 0, 0, 0};
    ushort8 x0 = *(const ushort8*)base;
    ushort8 x1 = (l >= 1) ? *(const ushort8*)(base - 2048) : z8;
    ushort8 x2 = (l >= 2) ? *(const ushort8*)(base - 2 * 2048) : z8;
    ushort8 x3 = (l >= 3) ? *(const ushort8*)(base - 3 * 2048) : z8;
    float4 cb0 = *(const float4*)(cb + d8);
    float4 cb1 = *(const float4*)(cb + d8 + 4);
    float bv[8] = {cb0.x, cb0.y, cb0.z, cb0.w, cb1.x, cb1.y, cb1.z, cb1.w};
    ushort8 o;
#pragma unroll
    for (int j = 0; j < 8; j++) {
        float4 wv = *(const float4*)(cw + (size_t)(d8 + j) * 4);
        float acc = bv[j];
        acc = fmaf(b2f(x0[j]), wv.w, acc);
        acc = fmaf(b2f(x1[j]), wv.z, acc);
        acc = fmaf(b2f(x2[j]), wv.y, acc);
        acc = fmaf(b2f(x3[j]), wv.x, acc);
        o[j] = f2b(siluf(acc));
    }
    *(ushort8*)(aConvB + (size_t)bl * 2048 + d8) = o;
}

// ---------------------------------------------------------------------------
// Chunk-parallel scan, 64 chunks x 16 steps, bf16 datapath incl. hend.
// prod factorization: chunk prod[s] = expA[s]^CH * prod(delta).
// hendB idx(b,c,s,d) = (((b*64+c)*16+s)<<11)+d ; P idx = (b*64+c)*2048+d.
__global__ __launch_bounds__(256) void scan_phaseA(
    const unsigned short* __restrict__ deltaB,
    const unsigned short* __restrict__ aConvB,
    const float* __restrict__ bc32, const float* __restrict__ A_param,
    unsigned short* __restrict__ hendB, float* __restrict__ Pd)
{
    int blk = blockIdx.x;                      // 1024
    int d = ((blk & 7) << 8) + threadIdx.x;
    int c = (blk >> 3) & 63;
    int b = blk >> 9;
    float expA[16], h[16];
#pragma unroll
    for (int s = 0; s < 16; s++) {
        expA[s] = expf(-A_param[d * 16 + s]);
        h[s] = 0.f;
    }
    float P = 1.f;
    int r0 = b * LSEQ + c * CH;
    const unsigned short* dp = deltaB + (size_t)r0 * D_MODEL + d;
    const unsigned short* ap = aConvB + (size_t)r0 * D_MODEL + d;
    const float4* bp = (const float4*)(bc32 + (size_t)r0 * 32);
    float dlt = b2f(*dp), av = b2f(*ap);
    float4 B0 = bp[0], B1 = bp[1], B2 = bp[2], B3 = bp[3];
    for (int l = 0; l < CH; l++) {
        dp += 2048; ap += 2048; bp += 8;       // prefetch l+1 (lands in ws, safe)
        float nd = b2f(*dp), na = b2f(*ap);
        float4 nB0 = bp[0], nB1 = bp[1], nB2 = bp[2], nB3 = bp[3];
        float Bv[16] = {B0.x, B0.y, B0.z, B0.w, B1.x, B1.y, B1.z, B1.w,
                        B2.x, B2.y, B2.z, B2.w, B3.x, B3.y, B3.z, B3.w};
        float x = dlt * av;
        P *= dlt;
#pragma unroll
        for (int s = 0; s < 16; s++)
            h[s] = fmaf(expA[s] * dlt, h[s], Bv[s] * x);
        dlt = nd; av = na; B0 = nB0; B1 = nB1; B2 = nB2; B3 = nB3;
    }
    size_t base = (((size_t)(b * 64 + c) * 16) << 11) + d;
#pragma unroll
    for (int s = 0; s < 16; s++)
        hendB[base + ((size_t)s << 11)] = f2b(h[s]);
    Pd[(size_t)(b * 64 + c) * 2048 + d] = P;
}

// chunk prefix: overwrite hendB[c] with state ENTERING chunk c
__global__ __launch_bounds__(256) void scan_phaseB2(
    unsigned short* __restrict__ hendB, const float* __restrict__ Pd,
    const float* __restrict__ A_param)
{
    int t = blockIdx.x * 256 + threadIdx.x;    // 65536
    int d = t & 2047, s = (t >> 11) & 15, b = t >> 15;
    float e = expf(-A_param[d * 16 + s]);
    float e2 = e * e, e4 = e2 * e2, e8 = e4 * e4;
    float eCH = e8 * e8;                       // expA^16
    size_t idx = (((size_t)(b * 64) * 16 + s) << 11) + d;
    const size_t cs = (size_t)16 << 11;
    size_t pidx = (size_t)(b * 64) * 2048 + d;
    float h = 0.f;
    float he = b2f(hendB[idx]), P = Pd[pidx];
    for (int c = 0; c < NCH; c++) {
        size_t nidx = idx + cs;
        float nhe = b2f(hendB[nidx]);          // prefetch (lands in ws, safe)
        float nP = Pd[pidx + 2048];
        hendB[idx] = f2b(h);
        h = fmaf(eCH * P, h, he);
        idx = nidx; pidx += 2048; he = nhe; P = nP;
    }
}

__global__ __launch_bounds__(256) void scan_phaseC(
    const unsigned short* __restrict__ deltaB,
    const unsigned short* __restrict__ aConvB,
    const unsigned short* __restrict__ gateB,
    const float* __restrict__ bc32,
    const float* __restrict__ A_param, const float* __restrict__ D_param,
    const unsigned short* __restrict__ hendB, unsigned short* __restrict__ outB)
{
    int blk = blockIdx.x;                      // 1024
    int d = ((blk & 7) << 8) + threadIdx.x;
    int c = (blk >> 3) & 63;
    int b = blk >> 9;
    float expA[16], h[16];
    size_t base = (((size_t)(b * 64 + c) * 16) << 11) + d;
#pragma unroll
    for (int s = 0; s < 16; s++) {
        expA[s] = expf(-A_param[d * 16 + s]);
        h[s] = b2f(hendB[base + ((size_t)s << 11)]);
    }
    float Dp = D_param[d];
    int r0 = b * LSEQ + c * CH;
    const unsigned short* dp = deltaB + (size_t)r0 * D_MODEL + d;
    const unsigned short* ap = aConvB + (size_t)r0 * D_MODEL + d;
    const unsigned short* gp = gateB + (size_t)r0 * 2048 + d;
    const float4* bp = (const float4*)(bc32 + (size_t)r0 * 32);
    unsigned short* op = outB + (size_t)r0 * D_MODEL + d;
    float dlt = b2f(*dp), av = b2f(*ap), g = b2f(*gp);
    float4 B0 = bp[0], B1 = bp[1], B2 = bp[2], B3 = bp[3];
    float4 C0 = bp[4], C1 = bp[5], C2 = bp[6], C3 = bp[7];
    for (int l = 0; l < CH; l++) {
        dp += 2048; ap += 2048; gp += 2048; bp += 8;
        float nd = b2f(*dp), na = b2f(*ap), ng = b2f(*gp);
        float4 nB0 = bp[0], nB1 = bp[1], nB2 = bp[2], nB3 = bp[3];
        float4 nC0 = bp[4], nC1 = bp[5], nC2 = bp[6], nC3 = bp[7];
        float Bv[16] = {B0.x, B0.y, B0.z, B0.w, B1.x, B1.y, B1.z, B1.w,
                        B2.x, B2.y, B2.z, B2.w, B3.x, B3.y, B3.z, B3.w};
        float Cv[16] = {C0.x, C0.y, C0.z, C0.w, C1.x, C1.y, C1.z, C1.w,
                        C2.x, C2.y, C2.z, C2.w, C3.x, C3.y, C3.z, C3.w};
        float x = dlt * av;
        float acc = 0.f;
#pragma unroll
        for (int s = 0; s < 16; s++) {
            float Ab = expA[s] * dlt;
            h[s] = fmaf(Ab, h[s], Bv[s] * x);
            acc = fmaf(h[s], Cv[s], acc);
        }
        *op = f2b((acc + Dp * av) * siluf(g));
        op += D_MODEL;
        dlt = nd; av = na; g = ng;
        B0 = nB0; B1 = nB1; B2 = nB2; B3 = nB3;
        C0 = nC0; C1 = nC1; C2 = nC2; C3 = nC3;
    }
}

extern "C" void kernel_launch(void* const* d_in, const int* in_sizes, int n_in,
                              void* d_out, int out_size, void* d_ws, size_t ws_size,
                              hipStream_t stream) {
    const float* seq = (const float*)d_in[0];
    const float* w_in = (const float*)d_in[1];
    const float* w_out = (const float*)d_in[2];
    const float* w_B = (const float*)d_in[3];
    const float* w_C = (const float*)d_in[4];
    const float* w_D1 = (const float*)d_in[5];
    const float* w_D2 = (const float*)d_in[6];
    const float* conv_w = (const float*)d_in[7];
    const float* conv_b = (const float*)d_in[8];
    const float* A_param = (const float*)d_in[9];
    const float* D_param = (const float*)d_in[10];
    float* out = (float*)d_out;

    // fp32 region (floats)
    float* bc32  = (float*)d_ws;                   // 65,536
    float* part  = bc32 + (size_t)65536;           // 2,621,440 (dead after reduce)
    float* part6 = part + (size_t)2621440;         // 8,388,608 (gemm6 partials)
    float* Pd    = part;                           // overlay: 262,144 ✓ (part dead)
    unsigned short* hendB = (unsigned short*)part6;  // overlay: 4,194,304 u16 ✓
                                                   //  (dead before gemm6 writes)
    // bf16 region
    unsigned short* seq_b  = (unsigned short*)(part6 + 8388608);
    unsigned short* win_b  = seq_b + (size_t)2097152;
    unsigned short* wout_b = win_b + (size_t)4194304;
    unsigned short* wbcd_b = wout_b + (size_t)2097152;  // [160,2048]
    unsigned short* wd2_b  = wbcd_b + (size_t)327680;   // [2048,128]
    unsigned short* aB     = wd2_b + (size_t)262144;    // [2048,2048]
    unsigned short* aConvB = aB + (size_t)4194304;      // [2048,2048]
    unsigned short* deltaB = aConvB + (size_t)4194304;  // [2048,2048]
    unsigned short* gateB  = deltaB + (size_t)4194304;  // [2048,2048]
    unsigned short* outB   = gateB + (size_t)4194304;   // [2048,2048]
    unsigned short* bcdB   = outB + (size_t)4194304;    // [2048,160]

    // 0) casts
    cast_all<<<dim3(4384), 256, 0, stream>>>(seq, w_in, w_out, w_B, w_C, w_D1, w_D2,
                                             seq_b, win_b, wout_b, wbcd_b, wd2_b);
    // 1) [a|gate] = seq @ w_in^T  [2048 x 4096] K=1024; both halves bf16
    gemm_db<64><<<dim3(64, 16), 256, 0, stream>>>(seq_b, 1024, win_b, 1024,
                                                  (float*)aB, 2048, 0, 4096, 1024,
                                                  nullptr, gateB, 5);
    // 2) conv + SiLU (bf16 in/out, 8-wide)
    conv_silu8<<<dim3(2048), 256, 0, stream>>>(aB, conv_w, conv_b, aConvB);
    // 3) bcd split-K x8, TN=64 (x=2 cols 128..191 read OOB rows of wbcd_b
    //    into wd2_b — allocated, masked at store)
    gemm_db<64><<<dim3(3, 16, 8), 256, 0, stream>>>(aConvB, 2048, wbcd_b, 2048,
                                                    part, 160, 327680, 160, 256,
                                                    nullptr, nullptr, 0);
    bcd_reduce<<<dim3(1280), 256, 0, stream>>>(part, bcdB, bc32);
    // 4) deltaB = bf16(softplus(D + d1 @ wD2^T))  [2048 x 2048] K=128
    gemm_db<64><<<dim3(32, 16), 256, 0, stream>>>(bcdB + 32, 160, wd2_b, 128,
                                                  (float*)deltaB, 2048, 0, 2048, 128,
                                                  D_param, nullptr, 2);
    // 5) chunk-parallel scan (64 chunks x 16 steps; bf16 datapath incl. hend)
    scan_phaseA<<<dim3(1024), 256, 0, stream>>>(deltaB, aConvB, bc32, A_param,
                                                hendB, Pd);
    scan_phaseB2<<<dim3(256), 256, 0, stream>>>(hendB, Pd, A_param);
    scan_phaseC<<<dim3(1024), 256, 0, stream>>>(deltaB, aConvB, gateB, bc32,
                                                A_param, D_param, hendB, outB);
    // 6) out = ssm_out @ w_out^T  [2048 x 1024] K=2048, TN=64 split-K x4
    gemm_db<64><<<dim3(16, 16, 4), 256, 0, stream>>>(outB, 2048, wout_b, 2048,
                                                     part6, 1024, 2097152, 1024, 512,
                                                     nullptr, nullptr, 0);
    out_reduce<<<dim3(2048), 256, 0, stream>>>(part6, out);
}

// Round 16
// 246.095 us; speedup vs baseline: 1.0278x; 1.0144x over previous
//
#include <hip/hip_runtime.h>
#include <math.h>

#define B_SZ 2
#define LSEQ 1024
#define D_INP 1024
#define D_MODEL 2048
#define D_STATE 16
#define D_DISCR 128
#define MROWS (B_SZ * LSEQ)
#define NCH 64
#define CH 16

typedef __bf16 bf16x8 __attribute__((ext_vector_type(8)));
typedef float f32x4 __attribute__((ext_vector_type(4)));
typedef unsigned short ushort8 __attribute__((ext_vector_type(8)));

__device__ __forceinline__ float siluf(float x) { return x / (1.f + expf(-x)); }
__device__ __forceinline__ float softplusf(float x) {
    return fmaxf(x, 0.f) + log1pf(expf(-fabsf(x)));
}
__device__ __forceinline__ unsigned short f2b(float f) {
    unsigned u = __builtin_bit_cast(unsigned, f);
    u = u + 0x7fffu + ((u >> 16) & 1u);
    return (unsigned short)(u >> 16);
}
__device__ __forceinline__ float b2f(unsigned short u) {
    return __builtin_bit_cast(float, ((unsigned)u) << 16);
}

// ---------------------------------------------------------------------------
__global__ __launch_bounds__(256) void cast_all(
    const float* __restrict__ seq, const float* __restrict__ w_in,
    const float* __restrict__ w_out, const float* __restrict__ w_B,
    const float* __restrict__ w_C, const float* __restrict__ w_D1,
    const float* __restrict__ w_D2,
    unsigned short* __restrict__ seq_b, unsigned short* __restrict__ win_b,
    unsigned short* __restrict__ wout_b, unsigned short* __restrict__ wbcd_b,
    unsigned short* __restrict__ wd2_b)
{
    int i = blockIdx.x * 256 + threadIdx.x;
    const float* src; unsigned short* dst; int off;
    if      (i < 262144)  { src = seq;  dst = seq_b;          off = i; }
    else if (i < 786432)  { src = w_in; dst = win_b;          off = i - 262144; }
    else if (i < 1048576) { src = w_out; dst = wout_b;        off = i - 786432; }
    else if (i < 1052672) { src = w_B;  dst = wbcd_b;         off = i - 1048576; }
    else if (i < 1056768) { src = w_C;  dst = wbcd_b + 32768; off = i - 1052672; }
    else if (i < 1089536) { src = w_D1; dst = wbcd_b + 65536; off = i - 1056768; }
    else if (i < 1122304) { src = w_D2; dst = wd2_b;          off = i - 1089536; }
    else return;
    const float4* p = (const float4*)(src + (size_t)off * 8);
    float4 a = p[0], b = p[1];
    ushort8 o = {f2b(a.x), f2b(a.y), f2b(a.z), f2b(a.w),
                 f2b(b.x), f2b(b.y), f2b(b.z), f2b(b.w)};
    *(ushort8*)(dst + (size_t)off * 8) = o;
}

// ---------------------------------------------------------------------------
// bf16 MFMA GEMM-NT — the measured optimum of the R5..R15 sweep (246.7 µs
// total at R12): 128xTN tile, BK=32, VGPR-staged single-slab-prefetch
// double buffer, 1 barrier/K-iter, XOR-swizzled unpadded LDS (0 conflicts).
// Sweep evidence: 128x64 @ 4 blocks/CU = 41 µs (R12); 64x64 @ 8/CU = 51 µs
// (R14: halved MFMA-per-barrier); depth-2 pipeline = 54 µs (R11: occupancy
// 36.8->20.2); global_load_lds staging = neutral (R13); padded LDS = 71 µs
// (R6: 2x LDS halved occupancy). ~390 TF here matches the m102 shape-curve
// plateau for source-level K-loops; beyond needs hand-asm vmcnt scheduling.
// Block does K-chunk [z*K, z*K+K) -> Cbase + z*partStride.
// TN=128: 4 waves 2x2, 4x4 frags; TN=64: waves row-stacked, 2x4 frags.
// B rows past N read unguarded (must be allocated); masked at store.
// epi: 0 fp32 store; 2 softplus(bias[col]+acc) -> bf16 (Cbase as u16);
//      5 split both-bf16: col<2048 -> (u16*)Cbase, col>=2048 -> C2.
template <int TN>
__global__ __launch_bounds__(256) void gemm_db(
    const unsigned short* __restrict__ A, int lda,
    const unsigned short* __restrict__ B, int ldb,
    float* __restrict__ Cbase, int ldc, size_t partStride,
    int N, int K, const float* __restrict__ bias,
    unsigned short* __restrict__ C2, int epi)
{
    __shared__ unsigned short As[2][128 * 32];
    __shared__ unsigned short Bs[2][TN * 32];
    const int t = threadIdx.x;
    const int w = t >> 6, lane = t & 63;
    const int fr = lane & 15, fq = lane >> 4;
    const int row0 = blockIdx.y * 128, col0 = blockIdx.x * TN;
    const int kz = blockIdx.z * K;
    const int sr = t >> 2, sq = t & 3;
    const int sqz = sq ^ ((sr >> 1) & 3);      // swizzled store chunk
    const int qa = fq ^ ((fr >> 1) & 3);       // swizzled read chunk

    constexpr int NI = (TN == 128) ? 4 : 2;
    const int rbase = (TN == 128) ? (w >> 1) * 64 : w * 32;
    const int cbase = (TN == 128) ? (w & 1) * 64 : 0;

    const unsigned short* gA0 = A + (size_t)(row0 + sr) * lda + kz + sq * 8;
    const unsigned short* gA1 = gA0 + (size_t)64 * lda;
    const unsigned short* gB0 = B + (size_t)(col0 + sr) * ldb + kz + sq * 8;
    const unsigned short* gB1 = gB0 + (size_t)64 * ldb;

    f32x4 acc[NI][4];
#pragma unroll
    for (int i = 0; i < NI; i++)
#pragma unroll
        for (int j = 0; j < 4; j++) acc[i][j] = (f32x4){0.f, 0.f, 0.f, 0.f};

    // prologue: stage slab 0 into buffer 0
    ushort8 a0 = *(const ushort8*)gA0;
    ushort8 a1 = *(const ushort8*)gA1;
    ushort8 b0 = *(const ushort8*)gB0;
    ushort8 b1;
    if (TN == 128) b1 = *(const ushort8*)gB1;
    *(ushort8*)&As[0][sr * 32 + sqz * 8] = a0;
    *(ushort8*)&As[0][(64 + sr) * 32 + sqz * 8] = a1;
    *(ushort8*)&Bs[0][sr * 32 + sqz * 8] = b0;
    if (TN == 128) *(ushort8*)&Bs[0][(64 + sr) * 32 + sqz * 8] = b1;
    __syncthreads();

    int buf = 0;
    for (int k0 = 0; k0 < K; k0 += 32) {
        const bool more = (k0 + 32 < K);
        if (more) {                        // next-slab loads in flight
            gA0 += 32; gA1 += 32; gB0 += 32; gB1 += 32;
            a0 = *(const ushort8*)gA0;
            a1 = *(const ushort8*)gA1;
            b0 = *(const ushort8*)gB0;
            if (TN == 128) b1 = *(const ushort8*)gB1;
        }
        bf16x8 af[NI], bfr[4];
#pragma unroll
        for (int i = 0; i < NI; i++) {
            ushort8 u = *(const ushort8*)&As[buf][(rbase + i * 16 + fr) * 32 + qa * 8];
            af[i] = __builtin_bit_cast(bf16x8, u);
        }
#pragma unroll
        for (int j = 0; j < 4; j++) {
            ushort8 u = *(const ushort8*)&Bs[buf][(cbase + j * 16 + fr) * 32 + qa * 8];
            bfr[j] = __builtin_bit_cast(bf16x8, u);
        }
#pragma unroll
        for (int i = 0; i < NI; i++)
#pragma unroll
            for (int j = 0; j < 4; j++)
                acc[i][j] = __builtin_amdgcn_mfma_f32_16x16x32_bf16(
                    af[i], bfr[j], acc[i][j], 0, 0, 0);
        if (more) {
            int nb = buf ^ 1;              // vmcnt wait lands here, post-MFMA
            *(ushort8*)&As[nb][sr * 32 + sqz * 8] = a0;
            *(ushort8*)&As[nb][(64 + sr) * 32 + sqz * 8] = a1;
            *(ushort8*)&Bs[nb][sr * 32 + sqz * 8] = b0;
            if (TN == 128) *(ushort8*)&Bs[nb][(64 + sr) * 32 + sqz * 8] = b1;
            __syncthreads();
            buf = nb;
        }
    }

    float* C = Cbase + (size_t)blockIdx.z * partStride;
#pragma unroll
    for (int i = 0; i < NI; i++) {
#pragma unroll
        for (int r = 0; r < 4; r++) {
            int row = row0 + rbase + i * 16 + fq * 4 + r;
#pragma unroll
            for (int j = 0; j < 4; j++) {   // j-inner: contiguous write runs
                int col = col0 + cbase + j * 16 + fr;
                if (col >= N) continue;
                float v = acc[i][j][r];
                if (epi == 0) C[(size_t)row * ldc + col] = v;
                else if (epi == 2)
                    ((unsigned short*)Cbase)[(size_t)row * ldc + col] =
                        f2b(softplusf(bias[col] + v));
                else {
                    unsigned short v16 = f2b(v);
                    if (col < 2048) ((unsigned short*)Cbase)[(size_t)row * 2048 + col] = v16;
                    else C2[(size_t)row * 2048 + col - 2048] = v16;
                }
            }
        }
    }
}

// ---------------------------------------------------------------------------
__global__ __launch_bounds__(256) void bcd_reduce(
    const float* __restrict__ part, unsigned short* __restrict__ bcdB,
    float* __restrict__ bc32)
{
    int t = blockIdx.x * 256 + threadIdx.x;
    if (t >= 327680) return;
    float s = 0.f;
#pragma unroll
    for (int z = 0; z < 8; z++) s += part[(size_t)z * 327680 + t];
    bcdB[t] = f2b(s);
    int col = t % 160;
    if (col < 32) bc32[(size_t)(t / 160) * 32 + col] = s;
}

// sum 4 split-K partials of gemm6 -> final out
__global__ __launch_bounds__(256) void out_reduce(
    const float* __restrict__ part, float* __restrict__ out)
{
    int i = blockIdx.x * 256 + threadIdx.x;    // 524288 float4 groups
    float4 p0 = ((const float4*)part)[i];
    float4 p1 = ((const float4*)(part + 2097152))[i];
    float4 p2 = ((const float4*)(part + 4194304))[i];
    float4 p3 = ((const float4*)(part + 6291456))[i];
    float4 o = {p0.x + p1.x + p2.x + p3.x, p0.y + p1.y + p2.y + p3.y,
                p0.z + p1.z + p2.z + p3.z, p0.w + p1.w + p2.w + p3.w};
    ((float4*)out)[i] = o;
}

// ---------------------------------------------------------------------------
// depthwise causal conv1d (K=4) + bias + SiLU; bf16 in/out, 8 d's per thread
__global__ __launch_bounds__(256) void conv_silu8(
    const unsigned short* __restrict__ aB,
    const float* __restrict__ cw, const float* __restrict__ cb,
    unsigned short* __restrict__ aConvB)
{
    int idx = blockIdx.x * 256 + threadIdx.x;      // 524288
    int d8 = (idx & 255) << 3;
    int bl = idx >> 8;
    int l = bl & (LSEQ - 1);
    const unsigned short* base = aB + (size_t)bl * 2048 + d8;
    const ushort8 z8 = {0, 0, 0, 0, 0, 0, 0, 0};
    ushort8 x0 = *(const ushort8*)base;
    ushort8 x1 = (l >= 1) ? *(const ushort8*)(base - 2048) : z8;
    ushort8 x2 = (l >= 2) ? *(const ushort8*)(base - 2 * 2048) : z8;
    ushort8 x3 = (l >= 3) ? *(const ushort8*)(base - 3 * 2048) : z8;
    float4 cb0 = *(const float4*)(cb + d8);
    float4 cb1 = *(const float4*)(cb + d8 + 4);
    float bv[8] = {cb0.x, cb0.y, cb0.z, cb0.w, cb1.x, cb1.y, cb1.z, cb1.w};
    ushort8 o;
#pragma unroll
    for (int j = 0; j < 8; j++) {
        float4 wv = *(const float4*)(cw + (size_t)(d8 + j) * 4);
        float acc = bv[j];
        acc = fmaf(b2f(x0[j]), wv.w, acc);
        acc = fmaf(b2f(x1[j]), wv.z, acc);
        acc = fmaf(b2f(x2[j]), wv.y, acc);
        acc = fmaf(b2f(x3[j]), wv.x, acc);
        o[j] = f2b(siluf(acc));
    }
    *(ushort8*)(aConvB + (size_t)bl * 2048 + d8) = o;
}

// ---------------------------------------------------------------------------
// Chunk-parallel scan, 64 chunks x 16 steps, bf16 inputs (fp32 compute,
// fp32 hend — R15's bf16-hend was neutral-negative, reverted).
// prod factorization: chunk prod[s] = expA[s]^CH * prod(delta); phase A
// stores only P = prod(delta) (1 float), phase B rebuilds expA^16 by squaring.
// hend idx(b,c,s,d) = (((b*64+c)*16+s)<<11)+d ; P idx = (b*64+c)*2048+d.
__global__ __launch_bounds__(256) void scan_phaseA(
    const unsigned short* __restrict__ deltaB,
    const unsigned short* __restrict__ aConvB,
    const float* __restrict__ bc32, const float* __restrict__ A_param,
    float* __restrict__ hend, float* __restrict__ Pd)
{
    int blk = blockIdx.x;                      // 1024
    int d = ((blk & 7) << 8) + threadIdx.x;
    int c = (blk >> 3) & 63;
    int b = blk >> 9;
    float expA[16], h[16];
#pragma unroll
    for (int s = 0; s < 16; s++) {
        expA[s] = expf(-A_param[d * 16 + s]);
        h[s] = 0.f;
    }
    float P = 1.f;
    int r0 = b * LSEQ + c * CH;
    const unsigned short* dp = deltaB + (size_t)r0 * D_MODEL + d;
    const unsigned short* ap = aConvB + (size_t)r0 * D_MODEL + d;
    const float4* bp = (const float4*)(bc32 + (size_t)r0 * 32);
    float dlt = b2f(*dp), av = b2f(*ap);
    float4 B0 = bp[0], B1 = bp[1], B2 = bp[2], B3 = bp[3];
    for (int l = 0; l < CH; l++) {
        dp += 2048; ap += 2048; bp += 8;       // prefetch l+1 (lands in ws, safe)
        float nd = b2f(*dp), na = b2f(*ap);
        float4 nB0 = bp[0], nB1 = bp[1], nB2 = bp[2], nB3 = bp[3];
        float Bv[16] = {B0.x, B0.y, B0.z, B0.w, B1.x, B1.y, B1.z, B1.w,
                        B2.x, B2.y, B2.z, B2.w, B3.x, B3.y, B3.z, B3.w};
        float x = dlt * av;
        P *= dlt;
#pragma unroll
        for (int s = 0; s < 16; s++)
            h[s] = fmaf(expA[s] * dlt, h[s], Bv[s] * x);
        dlt = nd; av = na; B0 = nB0; B1 = nB1; B2 = nB2; B3 = nB3;
    }
    size_t base = (((size_t)(b * 64 + c) * 16) << 11) + d;
#pragma unroll
    for (int s = 0; s < 16; s++)
        hend[base + ((size_t)s << 11)] = h[s];
    Pd[(size_t)(b * 64 + c) * 2048 + d] = P;
}

// chunk prefix: overwrite hend[c] with state ENTERING chunk c
__global__ __launch_bounds__(256) void scan_phaseB2(
    float* __restrict__ hend, const float* __restrict__ Pd,
    const float* __restrict__ A_param)
{
    int t = blockIdx.x * 256 + threadIdx.x;    // 65536
    int d = t & 2047, s = (t >> 11) & 15, b = t >> 15;
    float e = expf(-A_param[d * 16 + s]);
    float e2 = e * e, e4 = e2 * e2, e8 = e4 * e4;
    float eCH = e8 * e8;                       // expA^16
    size_t idx = (((size_t)(b * 64) * 16 + s) << 11) + d;
    const size_t cs = (size_t)16 << 11;
    size_t pidx = (size_t)(b * 64) * 2048 + d;
    float h = 0.f;
    float he = hend[idx], P = Pd[pidx];
    for (int c = 0; c < NCH; c++) {
        size_t nidx = idx + cs;
        float nhe = hend[nidx];                // prefetch (lands in ws, safe)
        float nP = Pd[pidx + 2048];
        hend[idx] = h;
        h = fmaf(eCH * P, h, he);
        idx = nidx; pidx += 2048; he = nhe; P = nP;
    }
}

__global__ __launch_bounds__(256) void scan_phaseC(
    const unsigned short* __restrict__ deltaB,
    const unsigned short* __restrict__ aConvB,
    const unsigned short* __restrict__ gateB,
    const float* __restrict__ bc32,
    const float* __restrict__ A_param, const float* __restrict__ D_param,
    const float* __restrict__ hend, unsigned short* __restrict__ outB)
{
    int blk = blockIdx.x;                      // 1024
    int d = ((blk & 7) << 8) + threadIdx.x;
    int c = (blk >> 3) & 63;
    int b = blk >> 9;
    float expA[16], h[16];
    size_t base = (((size_t)(b * 64 + c) * 16) << 11) + d;
#pragma unroll
    for (int s = 0; s < 16; s++) {
        expA[s] = expf(-A_param[d * 16 + s]);
        h[s] = hend[base + ((size_t)s << 11)];
    }
    float Dp = D_param[d];
    int r0 = b * LSEQ + c * CH;
    const unsigned short* dp = deltaB + (size_t)r0 * D_MODEL + d;
    const unsigned short* ap = aConvB + (size_t)r0 * D_MODEL + d;
    const unsigned short* gp = gateB + (size_t)r0 * 2048 + d;
    const float4* bp = (const float4*)(bc32 + (size_t)r0 * 32);
    unsigned short* op = outB + (size_t)r0 * D_MODEL + d;
    float dlt = b2f(*dp), av = b2f(*ap), g = b2f(*gp);
    float4 B0 = bp[0], B1 = bp[1], B2 = bp[2], B3 = bp[3];
    float4 C0 = bp[4], C1 = bp[5], C2 = bp[6], C3 = bp[7];
    for (int l = 0; l < CH; l++) {
        dp += 2048; ap += 2048; gp += 2048; bp += 8;
        float nd = b2f(*dp), na = b2f(*ap), ng = b2f(*gp);
        float4 nB0 = bp[0], nB1 = bp[1], nB2 = bp[2], nB3 = bp[3];
        float4 nC0 = bp[4], nC1 = bp[5], nC2 = bp[6], nC3 = bp[7];
        float Bv[16] = {B0.x, B0.y, B0.z, B0.w, B1.x, B1.y, B1.z, B1.w,
                        B2.x, B2.y, B2.z, B2.w, B3.x, B3.y, B3.z, B3.w};
        float Cv[16] = {C0.x, C0.y, C0.z, C0.w, C1.x, C1.y, C1.z, C1.w,
                        C2.x, C2.y, C2.z, C2.w, C3.x, C3.y, C3.z, C3.w};
        float x = dlt * av;
        float acc = 0.f;
#pragma unroll
        for (int s = 0; s < 16; s++) {
            float Ab = expA[s] * dlt;
            h[s] = fmaf(Ab, h[s], Bv[s] * x);
            acc = fmaf(h[s], Cv[s], acc);
        }
        *op = f2b((acc + Dp * av) * siluf(g));
        op += D_MODEL;
        dlt = nd; av = na; g = ng;
        B0 = nB0; B1 = nB1; B2 = nB2; B3 = nB3;
        C0 = nC0; C1 = nC1; C2 = nC2; C3 = nC3;
    }
}

extern "C" void kernel_launch(void* const* d_in, const int* in_sizes, int n_in,
                              void* d_out, int out_size, void* d_ws, size_t ws_size,
                              hipStream_t stream) {
    const float* seq = (const float*)d_in[0];
    const float* w_in = (const float*)d_in[1];
    const float* w_out = (const float*)d_in[2];
    const float* w_B = (const float*)d_in[3];
    const float* w_C = (const float*)d_in[4];
    const float* w_D1 = (const float*)d_in[5];
    const float* w_D2 = (const float*)d_in[6];
    const float* conv_w = (const float*)d_in[7];
    const float* conv_b = (const float*)d_in[8];
    const float* A_param = (const float*)d_in[9];
    const float* D_param = (const float*)d_in[10];
    float* out = (float*)d_out;

    // fp32 region (floats)
    float* bc32  = (float*)d_ws;                   // 65,536
    float* part  = bc32 + (size_t)65536;           // 2,621,440 (dead after reduce)
    float* part6 = part + (size_t)2621440;         // 8,388,608 (gemm6 partials)
    float* Pd    = part;                           // overlay: 262,144 ✓ (part dead)
    float* hend  = part6;                          // overlay: 4,194,304 ✓ (hend dead
                                                   //  before gemm6 writes part6)
    // bf16 region
    unsigned short* seq_b  = (unsigned short*)(part6 + 8388608);
    unsigned short* win_b  = seq_b + (size_t)2097152;
    unsigned short* wout_b = win_b + (size_t)4194304;
    unsigned short* wbcd_b = wout_b + (size_t)2097152;  // [160,2048]
    unsigned short* wd2_b  = wbcd_b + (size_t)327680;   // [2048,128]
    unsigned short* aB     = wd2_b + (size_t)262144;    // [2048,2048]
    unsigned short* aConvB = aB + (size_t)4194304;      // [2048,2048]
    unsigned short* deltaB = aConvB + (size_t)4194304;  // [2048,2048]
    unsigned short* gateB  = deltaB + (size_t)4194304;  // [2048,2048]
    unsigned short* outB   = gateB + (size_t)4194304;   // [2048,2048]
    unsigned short* bcdB   = outB + (size_t)4194304;    // [2048,160]

    // 0) casts
    cast_all<<<dim3(4384), 256, 0, stream>>>(seq, w_in, w_out, w_B, w_C, w_D1, w_D2,
                                             seq_b, win_b, wout_b, wbcd_b, wd2_b);
    // 1) [a|gate] = seq @ w_in^T  [2048 x 4096] K=1024; both halves bf16
    gemm_db<64><<<dim3(64, 16), 256, 0, stream>>>(seq_b, 1024, win_b, 1024,
                                                  (float*)aB, 2048, 0, 4096, 1024,
                                                  nullptr, gateB, 5);
    // 2) conv + SiLU (bf16 in/out, 8-wide)
    conv_silu8<<<dim3(2048), 256, 0, stream>>>(aB, conv_w, conv_b, aConvB);
    // 3) bcd split-K x8, TN=64 (x=2 cols 128..191 read OOB rows of wbcd_b
    //    into wd2_b — allocated, masked at store)
    gemm_db<64><<<dim3(3, 16, 8), 256, 0, stream>>>(aConvB, 2048, wbcd_b, 2048,
                                                    part, 160, 327680, 160, 256,
                                                    nullptr, nullptr, 0);
    bcd_reduce<<<dim3(1280), 256, 0, stream>>>(part, bcdB, bc32);
    // 4) deltaB = bf16(softplus(D + d1 @ wD2^T))  [2048 x 2048] K=128
    gemm_db<64><<<dim3(32, 16), 256, 0, stream>>>(bcdB + 32, 160, wd2_b, 128,
                                                  (float*)deltaB, 2048, 0, 2048, 128,
                                                  D_param, nullptr, 2);
    // 5) chunk-parallel scan (64 chunks x 16 steps; bf16 datapath, fp32 hend)
    scan_phaseA<<<dim3(1024), 256, 0, stream>>>(deltaB, aConvB, bc32, A_param,
                                                hend, Pd);
    scan_phaseB2<<<dim3(256), 256, 0, stream>>>(hend, Pd, A_param);
    scan_phaseC<<<dim3(1024), 256, 0, stream>>>(deltaB, aConvB, gateB, bc32,
                                                A_param, D_param, hend, outB);
    // 6) out = ssm_out @ w_out^T  [2048 x 1024] K=2048, TN=64 split-K x4
    gemm_db<64><<<dim3(16, 16, 4), 256, 0, stream>>>(outB, 2048, wout_b, 2048,
                                                     part6, 1024, 2097152, 1024, 512,
                                                     nullptr, nullptr, 0);
    out_reduce<<<dim3(2048), 256, 0, stream>>>(part6, out);
}